// Round 16
// baseline (1250.731 us; speedup 1.0000x reference)
//
#include <hip/hip_runtime.h>
#include <math.h>

typedef unsigned short u16;
typedef unsigned long long u64;
typedef __attribute__((ext_vector_type(8))) short bf16x8;
typedef __attribute__((ext_vector_type(4))) float f32x4;
typedef __attribute__((ext_vector_type(8))) unsigned short ushort8;

// Problem constants
constexpr int kB = 64;     // batch
constexpr int kN = 196;    // tokens in X
constexpr int kC = 512;    // X channels
constexpr int kE = 512;    // embedding dim
constexpr int kH = 1024;   // hidden
constexpr int kV = 10000;  // vocab (= 625*16 exactly)
constexpr int kT = 20;     // steps
constexpr int kG4 = 4 * kH;   // 4096
constexpr int kKA = 1536;     // gates GEMM K (e|h)
constexpr int kLT = 625;      // logit col-tiles of 16

__device__ __forceinline__ float sigmoidf_(float x) { return 1.0f / (1.0f + expf(-x)); }

__device__ __forceinline__ u16 f2bf(float x) {
    unsigned u = __float_as_uint(x);
    u += 0x7FFF + ((u >> 16) & 1);
    return (u16)(u >> 16);
}
__device__ __forceinline__ float bf2f(u16 u) {
    return __uint_as_float((unsigned)u << 16);
}
__device__ __forceinline__ void splitbf(float x, u16& hi, u16& lo) {
    hi = f2bf(x);
    lo = f2bf(x - bf2f(hi));
}

// pack a (logit, col) pair into a monotonic u64 key for atomicMax argmax;
// ties resolve to LOWER index (np.argmax semantics)
__device__ __forceinline__ u64 packMI(float M, int I) {
    unsigned mb = __float_as_uint(M);
    mb = (mb & 0x80000000u) ? ~mb : (mb | 0x80000000u);
    return ((u64)mb << 32) | (u64)(0xFFFFFFFFu - (unsigned)I);
}

// ---- flag barrier (round-10 proven): single poller, relaxed polls ----
__device__ __forceinline__ void bumpCtr(int* c) {
    __syncthreads();
    if (threadIdx.x == 0) {
        __builtin_amdgcn_fence(__ATOMIC_RELEASE, "agent");
        __hip_atomic_fetch_add(c, 1, __ATOMIC_RELAXED, __HIP_MEMORY_SCOPE_AGENT);
    }
}
__device__ __forceinline__ void waitGE(const int* c, int target) {
    if (threadIdx.x == 0) {
        int it = 0;
        while (__hip_atomic_load(c, __ATOMIC_RELAXED, __HIP_MEMORY_SCOPE_AGENT) < target
               && it < (1 << 20)) {
            __builtin_amdgcn_s_sleep(8);
            ++it;
        }
        __builtin_amdgcn_fence(__ATOMIC_ACQUIRE, "agent");
    }
    __syncthreads();
}

// ---------------- setup kernels (run once per launch) ----------------

__global__ __launch_bounds__(256) void k_colsum(const float* __restrict__ X,
                                                float* __restrict__ XsP) {
    int gid = blockIdx.x * 256 + threadIdx.x;    // 4*64*512
    int c = gid & 511, b = (gid >> 9) & 63, ch = gid >> 15;
    const float* p = X + (size_t)b * kN * kC + (size_t)(ch * 49) * kC + c;
    float s = 0.f;
    for (int n = 0; n < 49; ++n) s += p[(size_t)n * kC];
    XsP[gid] = s;
}

__global__ __launch_bounds__(256) void k_colred(const float* __restrict__ XsP,
                                                float* __restrict__ XsT) {
    int gid = blockIdx.x * 256 + threadIdx.x;    // 64*512
    int b = gid >> 9, c = gid & 511;
    float s = 0.f;
#pragma unroll
    for (int ch = 0; ch < 4; ++ch) s += XsP[ch * 32768 + b * 512 + c];
    XsT[c * kB + b] = s;
}

// Unified fp32 setup GEMM from XsT (K=512).
__global__ __launch_bounds__(256) void k_setupgemm(const float* __restrict__ XsT,
                                                   const float* __restrict__ W_ih,
                                                   const float* __restrict__ b_ih,
                                                   const float* __restrict__ b_hh,
                                                   const float* __restrict__ Wc0,
                                                   const float* __restrict__ bc0,
                                                   const float* __restrict__ Wh0,
                                                   const float* __restrict__ bh0,
                                                   const float* __restrict__ Wlc,
                                                   const float* __restrict__ blc,
                                                   const float* __restrict__ blh,
                                                   float* __restrict__ gbP,
                                                   float* __restrict__ cBJ,
                                                   u16* __restrict__ hb0Hi,
                                                   u16* __restrict__ hb0Lo,
                                                   float* __restrict__ ctxc) {
    __shared__ float4 wt4[64][8];
    int t = threadIdx.x;
    int b = t & 63, q = t >> 6;
    int tile = blockIdx.x;

    const float* W; const float* bias; float scale; int ldw; int mode; int j;
    if (tile < 128) {
        j = tile * 32; W = W_ih + (size_t)kE * kG4 + j; ldw = kG4;
        bias = nullptr; scale = 1.f; mode = 0;
    } else if (tile < 160) {
        j = (tile - 128) * 32; W = Wc0 + j; ldw = kH;
        bias = bc0 + j; scale = 1.0f / 196.0f; mode = 1;
    } else if (tile < 192) {
        j = (tile - 160) * 32; W = Wh0 + j; ldw = kH;
        bias = bh0 + j; scale = 1.0f / 196.0f; mode = 2;
    } else {
        j = (tile - 192) * 32; W = Wlc + j; ldw = kE;
        bias = blc + j; scale = 1.f; mode = 3;
    }

    int lr = t >> 2, lq2 = (t & 3) * 2;
    float acc[8];
#pragma unroll
    for (int i = 0; i < 8; ++i) acc[i] = 0.f;

    for (int kt = 0; kt < kC; kt += 64) {
        const float* wrow = W + (size_t)(kt + lr) * ldw;
        float4 w0 = *reinterpret_cast<const float4*>(wrow + lq2 * 4);
        float4 w1 = *reinterpret_cast<const float4*>(wrow + lq2 * 4 + 4);
        __syncthreads();
        wt4[lr][lq2] = w0; wt4[lr][lq2 + 1] = w1;
        __syncthreads();
        const float* ap = XsT + (size_t)kt * kB + b;
#pragma unroll 8
        for (int kk = 0; kk < 64; ++kk) {
            float a = ap[kk * 64] * scale;
            float4 u0 = wt4[kk][q * 2];
            float4 u1 = wt4[kk][q * 2 + 1];
            acc[0] += a * u0.x; acc[1] += a * u0.y; acc[2] += a * u0.z; acc[3] += a * u0.w;
            acc[4] += a * u1.x; acc[5] += a * u1.y; acc[6] += a * u1.z; acc[7] += a * u1.w;
        }
    }
#pragma unroll
    for (int cc = 0; cc < 8; ++cc) {
        int col = q * 8 + cc;
        float v = acc[cc];
        if (mode == 0) {
            int jsrc = j + col;
            v += b_ih[jsrc] + b_hh[jsrc];
            int nd = ((jsrc & 1023) << 2) | (jsrc >> 10);
            gbP[(size_t)b * kG4 + nd] = v;
        } else if (mode == 1) {
            v = tanhf(v + bias[col]);
            cBJ[(size_t)b * kH + j + col] = v;
        } else if (mode == 2) {
            v = tanhf(v + bias[col]);
            u16 hi, lo; splitbf(v, hi, lo);
            hb0Hi[(size_t)b * kH + j + col] = hi;
            hb0Lo[(size_t)b * kH + j + col] = lo;
        } else {
            v += bias[col] + blh[j + col];
            ctxc[(size_t)b * kE + j + col] = v;
        }
    }
}

// transpose + bf16 hi/lo split: dst[n][k] from src[k][n]
__global__ __launch_bounds__(256) void k_wconv(const float* __restrict__ src,
                                               u16* __restrict__ dhi,
                                               u16* __restrict__ dlo,
                                               int ld, int n_valid, int pitch,
                                               int k_off, int nxTiles) {
    __shared__ float lds[64][65];
    int t = threadIdx.x;
    int nx = blockIdx.x % nxTiles, ky = blockIdx.x / nxTiles;
    int n0 = nx * 64, k0 = ky * 64;
    int c = t & 63, r0 = t >> 6;
#pragma unroll
    for (int i = 0; i < 16; ++i) {
        int r = r0 + i * 4;
        float v = (n0 + c < n_valid) ? src[(size_t)(k0 + r) * ld + n0 + c] : 0.f;
        lds[r][c] = v;
    }
    __syncthreads();
    int nl = t >> 2, kq = t & 3;
#pragma unroll
    for (int half = 0; half < 2; ++half) {
        ushort8 vh, vl;
#pragma unroll
        for (int jj = 0; jj < 8; ++jj) {
            u16 hi, lo; splitbf(lds[kq * 16 + half * 8 + jj][nl], hi, lo);
            vh[jj] = hi; vl[jj] = lo;
        }
        size_t o = (size_t)(n0 + nl) * pitch + k_off + k0 + kq * 16 + half * 8;
        *(ushort8*)(&dhi[o]) = vh;
        *(ushort8*)(&dlo[o]) = vl;
    }
}

// gate-interleaved transpose + bf16-HI-only for Wg
__global__ __launch_bounds__(256) void k_wgconv(const float* __restrict__ src,
                                                u16* __restrict__ dhi,
                                                int k_off) {
    __shared__ float lds[64][65];
    int t = threadIdx.x;
    int nx = blockIdx.x & 63, ky = blockIdx.x >> 6;
    int n0 = nx * 64, k0 = ky * 64;
    int c = t & 63, r0 = t >> 6;
#pragma unroll
    for (int i = 0; i < 16; ++i) {
        int r = r0 + i * 4;
        int nd = n0 + c;
        int nsrc = (nd & 3) * 1024 + (nd >> 2);
        lds[r][c] = src[(size_t)(k0 + r) * kG4 + nsrc];
    }
    __syncthreads();
    int nl = t >> 2, kq = t & 3;
#pragma unroll
    for (int half = 0; half < 2; ++half) {
        ushort8 vh;
#pragma unroll
        for (int jj = 0; jj < 8; ++jj) vh[jj] = f2bf(lds[kq * 16 + half * 8 + jj][nl]);
        size_t o = (size_t)(n0 + nl) * kKA + k_off + k0 + kq * 16 + half * 8;
        *(ushort8*)(&dhi[o]) = vh;
    }
}

// plain transpose + bf16-HI-only (for Wlh)
__global__ __launch_bounds__(256) void k_wconvh(const float* __restrict__ src,
                                                u16* __restrict__ dhi,
                                                int ld, int pitch, int nxTiles) {
    __shared__ float lds[64][65];
    int t = threadIdx.x;
    int nx = blockIdx.x % nxTiles, ky = blockIdx.x / nxTiles;
    int n0 = nx * 64, k0 = ky * 64;
    int c = t & 63, r0 = t >> 6;
#pragma unroll
    for (int i = 0; i < 16; ++i) {
        int r = r0 + i * 4;
        lds[r][c] = src[(size_t)(k0 + r) * ld + n0 + c];
    }
    __syncthreads();
    int nl = t >> 2, kq = t & 3;
#pragma unroll
    for (int half = 0; half < 2; ++half) {
        ushort8 vh;
#pragma unroll
        for (int jj = 0; jj < 8; ++jj) vh[jj] = f2bf(lds[kq * 16 + half * 8 + jj][nl]);
        size_t o = (size_t)(n0 + nl) * pitch + k0 + kq * 16 + half * 8;
        *(ushort8*)(&dhi[o]) = vh;
    }
}

// emb table -> bf16 hi/lo (whole table, once). grid 5000.
__global__ __launch_bounds__(256) void k_embconv(const float* __restrict__ emb,
                                                 u16* __restrict__ eh,
                                                 u16* __restrict__ el) {
    int gid = blockIdx.x * 256 + threadIdx.x;    // 1,280,000
    float4 v = *reinterpret_cast<const float4*>(emb + (size_t)gid * 4);
    u16 h0, l0, h1, l1, h2, l2, h3, l3;
    splitbf(v.x, h0, l0); splitbf(v.y, h1, l1);
    splitbf(v.z, h2, l2); splitbf(v.w, h3, l3);
    u64 ph = (u64)h0 | ((u64)h1 << 16) | ((u64)h2 << 32) | ((u64)h3 << 48);
    u64 pl = (u64)l0 | ((u64)l1 << 16) | ((u64)l2 << 32) | ((u64)l3 << 48);
    *reinterpret_cast<u64*>(eh + (size_t)gid * 4) = ph;
    *reinterpret_cast<u64*>(el + (size_t)gid * 4) = pl;
}

__global__ __launch_bounds__(256) void k_out0(float* __restrict__ out) {
    int gid = blockIdx.x * 256 + threadIdx.x;      // 64*10000
    if (gid >= kB * kV) return;
    int b = gid / kV, v = gid - b * kV;
    out[(size_t)b * kT * kV + v] = (v == 1) ? 1.0f : 0.0f;
}

// ---------------- per-step kernels (2 per step) ----------------

struct StepP {
    u16 *hbHi0, *hbLo0, *hbHi1, *hbLo1;   // h activation, double-buffered
    float *cBJ, *gbP, *ctxc;
    u16 *CbHi, *CbLo;
    const u16 *WgHi, *WlhHi, *WoHi, *WoLo, *embHi, *embLo;
    const float *bout;
    float *lbuf0, *lbuf1;                  // logits, double-buffered
    float *Ssh;                            // [2][8][64] sum-exp shards
    u64 *Mxsh;                             // [2][8][64] packed (max|~idx) shards
    float *out;
    int *ctrs;
};

// resolve per-batch token of step-1 from Mx shards (kernel boundary = coherent)
__device__ __forceinline__ int resolveTok(const StepP& p, int step, int b) {
    if (step <= 1) return 1;   // START_IDX
    int slot = (step - 1) & 1;
    u64 best = 0;
#pragma unroll
    for (int sh = 0; sh < 8; ++sh) {
        u64 v = p.Mxsh[(slot * 8 + sh) * 64 + b];
        if (v > best) best = v;
    }
    return (int)(0xFFFFFFFFu - (unsigned)(best & 0xFFFFFFFFu));
}

// K1 (fused G + C + OW): grid 256 x 512 threads, all co-resident (<=1 blk/CU).
//   all blocks: tok resolve, gates GEMM + LSTM -> h, bump counter
//   blocks [0,32): wait all-gates-done, comb GEMM -> Cb (post-fence refetch ~1.3 MB only)
//   blocks [32,256): out-row step-1 (no fence needed)
__global__ __launch_bounds__(512) void k_stepGC(StepP p, int step) {
    __shared__ float sred[8][64][17];
    __shared__ int tok[64];
    __shared__ float lseArr[64];
    const int blk = blockIdx.x, t = threadIdx.x;
    const int l = t & 63, w = t >> 6, la = l & 15, lg = l >> 4;
    const int Pb = (step - 1) & 1, Qb = step & 1;

    if (t < 64) tok[t] = resolveTok(p, step, t);
    if (blk < 8 && t < 64) {
        int slot = step & 1;
        p.Ssh[(slot * 8 + blk) * 64 + t] = 0.f;
        p.Mxsh[(slot * 8 + blk) * 64 + t] = 0;
    }
    __syncthreads();

    // ---- gates GEMM (8-way wave-split-K, W hi-only, act hi+lo) ----
    const u16* hpHi = Pb ? p.hbHi1 : p.hbHi0;
    const u16* hpLo = Pb ? p.hbLo1 : p.hbLo0;
    u16* nHi = Qb ? p.hbHi1 : p.hbHi0;
    u16* nLo = Qb ? p.hbLo1 : p.hbLo0;
    const int n0 = blk * 16;
    {
        const int kb = w * 192 + lg * 8;
        const u16* wh = p.WgHi + (size_t)(n0 + la) * kKA + kb;
        int tk[4];
#pragma unroll
        for (int m = 0; m < 4; ++m) tk[m] = tok[m * 16 + la];

        bf16x8 wreg[6];
#pragma unroll
        for (int ks = 0; ks < 6; ++ks) wreg[ks] = *(const bf16x8*)(wh + ks * 32);

        f32x4 acc[4];
#pragma unroll
        for (int m = 0; m < 4; ++m) acc[m] = (f32x4){0.f, 0.f, 0.f, 0.f};
#pragma unroll
        for (int ks = 0; ks < 6; ++ks) {
            int kc = w * 192 + ks * 32;
#pragma unroll
            for (int m = 0; m < 4; ++m) {
                int row = m * 16 + la;
                bf16x8 ahi8, alo8;
                if (kc < kE) {
                    size_t o = (size_t)tk[m] * kE + kc + lg * 8;
                    ahi8 = *(const bf16x8*)(p.embHi + o);
                    alo8 = *(const bf16x8*)(p.embLo + o);
                } else {
                    size_t o = (size_t)row * kH + (kc - kE) + lg * 8;
                    ahi8 = *(const bf16x8*)(hpHi + o);
                    alo8 = *(const bf16x8*)(hpLo + o);
                }
                acc[m] = __builtin_amdgcn_mfma_f32_16x16x32_bf16(ahi8, wreg[ks], acc[m], 0, 0, 0);
                acc[m] = __builtin_amdgcn_mfma_f32_16x16x32_bf16(alo8, wreg[ks], acc[m], 0, 0, 0);
            }
        }
#pragma unroll
        for (int m = 0; m < 4; ++m)
#pragma unroll
            for (int r = 0; r < 4; ++r)
                sred[w][m * 16 + lg * 4 + r][la] = acc[m][r];
        __syncthreads();
        if (t < 256) {
            int b = t & 63, jl = (t >> 6) & 3;
            float g[4];
#pragma unroll
            for (int gi = 0; gi < 4; ++gi) {
                int cc = jl * 4 + gi;
                float s = p.gbP[(size_t)b * kG4 + n0 + cc];
#pragma unroll
                for (int wv = 0; wv < 8; ++wv) s += sred[wv][b][cc];
                g[gi] = s;
            }
            int jp = blk * 4 + jl;
            float cold = p.cBJ[b * kH + jp];
            float c2 = sigmoidf_(g[1]) * cold + sigmoidf_(g[0]) * tanhf(g[2]);
            float h2 = sigmoidf_(g[3]) * tanhf(c2);
            p.cBJ[b * kH + jp] = c2;
            u16 hh, hl; splitbf(h2, hh, hl);
            nHi[(size_t)b * kH + jp] = hh;
            nLo[(size_t)b * kH + jp] = hl;
        }
    }
    bumpCtr(p.ctrs);   // gates of this block complete (incl. h writes)

    if (blk < 32) {
        // ---- comb: wait for ALL gates (all 256 blocks co-resident -> no deadlock) ----
        waitGE(p.ctrs, 256 * step);
        const u16* hcHi = Qb ? p.hbHi1 : p.hbHi0;
        const u16* hcLo = Qb ? p.hbLo1 : p.hbLo0;
        const int kb = w * 128 + lg * 8;     // 8 waves x 128 K each
        const u16* wh = p.WlhHi + (size_t)(n0 + la) * kH + kb;
        bf16x8 wreg[4];
#pragma unroll
        for (int ks = 0; ks < 4; ++ks) wreg[ks] = *(const bf16x8*)(wh + ks * 32);
        f32x4 acc[4];
#pragma unroll
        for (int m = 0; m < 4; ++m) acc[m] = (f32x4){0.f, 0.f, 0.f, 0.f};
#pragma unroll
        for (int ks = 0; ks < 4; ++ks) {
            int ko = ks * 32;
#pragma unroll
            for (int m = 0; m < 4; ++m) {
                size_t o = (size_t)(m * 16 + la) * kH + kb + ko;
                bf16x8 ahi8 = *(const bf16x8*)(hcHi + o);
                bf16x8 alo8 = *(const bf16x8*)(hcLo + o);
                acc[m] = __builtin_amdgcn_mfma_f32_16x16x32_bf16(ahi8, wreg[ks], acc[m], 0, 0, 0);
                acc[m] = __builtin_amdgcn_mfma_f32_16x16x32_bf16(alo8, wreg[ks], acc[m], 0, 0, 0);
            }
        }
#pragma unroll
        for (int m = 0; m < 4; ++m)
#pragma unroll
            for (int r = 0; r < 4; ++r)
                sred[w][m * 16 + lg * 4 + r][la] = acc[m][r];
        __syncthreads();
        if (t < 256) {
            int b = t & 63, cq = (t >> 6) & 3;
            int tokb = tok[b];
#pragma unroll
            for (int i = 0; i < 4; ++i) {
                int cc = cq * 4 + i;
                int col = n0 + cc;
                float v = 0.f;
#pragma unroll
                for (int wv = 0; wv < 8; ++wv) v += sred[wv][b][cc];
                v += bf2f(p.embHi[(size_t)tokb * kE + col]) + bf2f(p.embLo[(size_t)tokb * kE + col]);
                v += p.ctxc[(size_t)b * kE + col];
                u16 hh, hl; splitbf(v, hh, hl);
                p.CbHi[(size_t)b * kE + col] = hh;
                p.CbLo[(size_t)b * kE + col] = hl;
            }
        }
    } else if (step > 1) {
        // ---- out-row step-1 (reads only step-1 data; no fence needed) ----
        int slot = (step - 1) & 1;
        if (t < 64) {
            float S = 0.f;
#pragma unroll
            for (int sh = 0; sh < 8; ++sh) S += p.Ssh[(slot * 8 + sh) * 64 + t];
            lseArr[t] = logf(S);
        }
        __syncthreads();
        const float* lb = slot ? p.lbuf1 : p.lbuf0;
        for (int idx = (blk - 32) * 512 + t; idx < kB * kV; idx += 224 * 512) {
            int b = idx / kV, c = idx - b * kV;
            __builtin_nontemporal_store(lb[(size_t)b * kV + c] - lseArr[b],
                                        &p.out[((size_t)b * kT + (step - 1)) * kV + c]);
        }
    }
}

// K2: logits GEMM, 512 threads, 8-way wave-split-K (K=64/wave), full bf16x3.
// grid 625 (one 16-col tile per block) + shard atomics.
__global__ __launch_bounds__(512) void k_stepL(StepP p, int step) {
    __shared__ float sred[8][64][17];
    __shared__ float redM[256], redS[256];
    __shared__ int redI[256];
    const int blk = blockIdx.x, t = threadIdx.x;
    const int l = t & 63, w = t >> 6, la = l & 15, lg = l >> 4;
    int slot = step & 1;
    float* lb = slot ? p.lbuf1 : p.lbuf0;
    int shard = blk & 7;
    const int c0 = blk * 16;
    const int kb = w * 64 + lg * 8;
    const u16* wh = p.WoHi + (size_t)(c0 + la) * kE + kb;
    const u16* wl = p.WoLo + (size_t)(c0 + la) * kE + kb;
    const u16* a0h = p.CbHi + (size_t)la * kE + kb;
    const u16* a0l = p.CbLo + (size_t)la * kE + kb;

    bf16x8 wh0 = *(const bf16x8*)(wh);
    bf16x8 wh1 = *(const bf16x8*)(wh + 32);
    bf16x8 wl0 = *(const bf16x8*)(wl);
    bf16x8 wl1 = *(const bf16x8*)(wl + 32);

    f32x4 acc[4];
#pragma unroll
    for (int m = 0; m < 4; ++m) acc[m] = (f32x4){0.f, 0.f, 0.f, 0.f};
#pragma unroll
    for (int m = 0; m < 4; ++m) {
        bf16x8 ah0 = *(const bf16x8*)(a0h + (size_t)m * 16 * kE);
        bf16x8 al0 = *(const bf16x8*)(a0l + (size_t)m * 16 * kE);
        bf16x8 ah1 = *(const bf16x8*)(a0h + (size_t)m * 16 * kE + 32);
        bf16x8 al1 = *(const bf16x8*)(a0l + (size_t)m * 16 * kE + 32);
        acc[m] = __builtin_amdgcn_mfma_f32_16x16x32_bf16(ah0, wh0, acc[m], 0, 0, 0);
        acc[m] = __builtin_amdgcn_mfma_f32_16x16x32_bf16(ah0, wl0, acc[m], 0, 0, 0);
        acc[m] = __builtin_amdgcn_mfma_f32_16x16x32_bf16(al0, wh0, acc[m], 0, 0, 0);
        acc[m] = __builtin_amdgcn_mfma_f32_16x16x32_bf16(ah1, wh1, acc[m], 0, 0, 0);
        acc[m] = __builtin_amdgcn_mfma_f32_16x16x32_bf16(ah1, wl1, acc[m], 0, 0, 0);
        acc[m] = __builtin_amdgcn_mfma_f32_16x16x32_bf16(al1, wh1, acc[m], 0, 0, 0);
    }
#pragma unroll
    for (int m = 0; m < 4; ++m)
#pragma unroll
        for (int r = 0; r < 4; ++r)
            sred[w][m * 16 + lg * 4 + r][la] = acc[m][r];
    __syncthreads();
    if (t < 256) {
        int b = t & 63, cq = (t >> 6) & 3;
        float vals[4];
#pragma unroll
        for (int i = 0; i < 4; ++i) {
            int cc = cq * 4 + i;
            float s = p.bout[c0 + cc];
#pragma unroll
            for (int wv = 0; wv < 8; ++wv) s += sred[wv][b][cc];
            vals[i] = s;
        }
        __builtin_nontemporal_store((f32x4){vals[0], vals[1], vals[2], vals[3]},
                                    (f32x4*)(lb + (size_t)b * kV + c0 + cq * 4));
        float m = vals[0]; int mi = 0;
#pragma unroll
        for (int i = 1; i < 4; ++i) if (vals[i] > m) { m = vals[i]; mi = i; }
        float se = 0.f;
#pragma unroll
        for (int i = 0; i < 4; ++i) se += __expf(vals[i] - m);
        redM[t] = m; redS[t] = se; redI[t] = c0 + cq * 4 + mi;
    }
    __syncthreads();
    if (t < 64) {
        float M = redM[t], S = redS[t]; int I = redI[t];
#pragma unroll
        for (int q2 = 1; q2 < 4; ++q2) {
            float m2 = redM[t + q2 * 64], s2 = redS[t + q2 * 64];
            int i2 = redI[t + q2 * 64];
            float Mn = fmaxf(M, m2);
            S = S * __expf(M - Mn) + s2 * __expf(m2 - Mn);
            if (m2 > M || (m2 == M && i2 < I)) I = i2;
            M = Mn;
        }
        float S0 = S * __expf(M);   // fold to absolute scale (M=0 reference)
        atomicAdd(&p.Ssh[(slot * 8 + shard) * 64 + t], S0);
        atomicMax(&p.Mxsh[(slot * 8 + shard) * 64 + t], packMI(M, I));
    }
}

// final out row (kT-1). grid 256.
__global__ __launch_bounds__(256) void k_stepO(StepP p) {
    __shared__ float lseArr[64];
    const int blk = blockIdx.x, t = threadIdx.x;
    int slot = (kT - 1) & 1;
    if (t < 64) {
        float S = 0.f;
#pragma unroll
        for (int sh = 0; sh < 8; ++sh) S += p.Ssh[(slot * 8 + sh) * 64 + t];
        lseArr[t] = logf(S);
    }
    __syncthreads();
    const float* lb = slot ? p.lbuf1 : p.lbuf0;
    for (int idx = blk * 256 + t; idx < kB * kV; idx += 256 * 256) {
        int b = idx / kV, c = idx - b * kV;
        __builtin_nontemporal_store(lb[(size_t)b * kV + c] - lseArr[b],
                                    &p.out[((size_t)b * kT + (kT - 1)) * kV + c]);
    }
}

// ---------------- launcher ----------------

extern "C" void kernel_launch(void* const* d_in, const int* in_sizes, int n_in,
                              void* d_out, int out_size, void* d_ws, size_t ws_size,
                              hipStream_t stream) {
    const float* X    = (const float*)d_in[0];
    const float* emb  = (const float*)d_in[1];
    const float* W_ih = (const float*)d_in[2];
    const float* b_ih = (const float*)d_in[3];
    const float* W_hh = (const float*)d_in[4];
    const float* b_hh = (const float*)d_in[5];
    // d_in[6..11]: Wa, ba, Wh, bh, Wo, bo — dead (softmax over size-1 axis => weights==1)
    const float* Wlh  = (const float*)d_in[12];
    const float* blh  = (const float*)d_in[13];
    const float* Wlc  = (const float*)d_in[14];
    const float* blc  = (const float*)d_in[15];
    const float* Wout = (const float*)d_in[16];
    const float* bout = (const float*)d_in[17];
    const float* Wc0  = (const float*)d_in[18];
    const float* bc0  = (const float*)d_in[19];
    const float* Wh0  = (const float*)d_in[20];
    const float* bh0  = (const float*)d_in[21];
    float* out = (float*)d_out;

    char* cur = (char*)d_ws;
    auto carve = [&](size_t bytes) { char* p = cur; cur += (bytes + 255) & ~(size_t)255; return p; };

    u16* hbHi0 = (u16*)carve((size_t)kB * kH * 2);
    u16* hbLo0 = (u16*)carve((size_t)kB * kH * 2);
    u16* hbHi1 = (u16*)carve((size_t)kB * kH * 2);
    u16* hbLo1 = (u16*)carve((size_t)kB * kH * 2);
    float* cBJ  = (float*)carve((size_t)kB * kH * 4);
    float* gbP  = (float*)carve((size_t)kB * kG4 * 4);
    float* ctxc = (float*)carve((size_t)kB * kE * 4);
    u16* CbHi   = (u16*)carve((size_t)kB * kE * 2);
    u16* CbLo   = (u16*)carve((size_t)kB * kE * 2);
    float* XsT  = (float*)carve((size_t)kC * kB * 4);
    float* XsP  = (float*)carve((size_t)4 * kB * kC * 4);
    u16* WgHi   = (u16*)carve((size_t)kG4 * kKA * 2);
    u16* WlhHi  = (u16*)carve((size_t)kE * kH * 2);
    u16* WoHi   = (u16*)carve((size_t)10048 * kE * 2);
    u16* WoLo   = (u16*)carve((size_t)10048 * kE * 2);
    u16* embHi  = (u16*)carve((size_t)10000 * kE * 2);
    u16* embLo  = (u16*)carve((size_t)10000 * kE * 2);
    float* lbuf0 = (float*)carve((size_t)kB * kV * 4);
    float* lbuf1 = (float*)carve((size_t)kB * kV * 4);
    float* Ssh   = (float*)carve((size_t)2 * 8 * 64 * 4);
    u64*   Mxsh  = (u64*)carve((size_t)2 * 8 * 64 * 8);
    int*   ctrs  = (int*)carve(256);

    hipMemsetAsync(ctrs, 0, 256, stream);   // replay-safe flag reset

    // one-time setup
    k_colsum<<<512, 256, 0, stream>>>(X, XsP);
    k_colred<<<128, 256, 0, stream>>>(XsP, XsT);
    k_setupgemm<<<208, 256, 0, stream>>>(XsT, W_ih, b_ih, b_hh, Wc0, bc0,
                                         Wh0, bh0, Wlc, blc, blh,
                                         gbP, cBJ, hbHi0, hbLo0, ctxc);
    k_out0<<<(kB * kV + 255) / 256, 256, 0, stream>>>(out);
    k_wgconv<<<64 * 8, 256, 0, stream>>>(W_ih, WgHi, 0);     // k 0..511 (e)
    k_wgconv<<<64 * 16, 256, 0, stream>>>(W_hh, WgHi, kE);   // k 512..1535 (h)
    k_wconvh<<<8 * 16, 256, 0, stream>>>(Wlh, WlhHi, kE, kH, 8);
    k_wconv<<<157 * 8, 256, 0, stream>>>(Wout, WoHi, WoLo, kV, kV, kE, 0, 157);
    k_embconv<<<5000, 256, 0, stream>>>(emb, embHi, embLo);

    StepP sp;
    sp.hbHi0 = hbHi0; sp.hbLo0 = hbLo0; sp.hbHi1 = hbHi1; sp.hbLo1 = hbLo1;
    sp.cBJ = cBJ; sp.gbP = gbP; sp.ctxc = ctxc;
    sp.CbHi = CbHi; sp.CbLo = CbLo;
    sp.WgHi = WgHi; sp.WlhHi = WlhHi;
    sp.WoHi = WoHi; sp.WoLo = WoLo; sp.embHi = embHi; sp.embLo = embLo;
    sp.bout = bout;
    sp.lbuf0 = lbuf0; sp.lbuf1 = lbuf1;
    sp.Ssh = Ssh; sp.Mxsh = Mxsh;
    sp.out = out;
    sp.ctrs = ctrs;

    for (int s = 1; s < kT; ++s) {
        k_stepGC<<<256, 512, 0, stream>>>(sp, s);
        k_stepL<<<kLT, 512, 0, stream>>>(sp, s);
    }
    k_stepO<<<256, 256, 0, stream>>>(sp);
}

// Round 17
// 1016.853 us; speedup vs baseline: 1.2300x; 1.2300x over previous
//
#include <hip/hip_runtime.h>
#include <math.h>

typedef unsigned short u16;
typedef unsigned long long u64;
typedef __attribute__((ext_vector_type(8))) short bf16x8;
typedef __attribute__((ext_vector_type(4))) float f32x4;
typedef __attribute__((ext_vector_type(8))) unsigned short ushort8;

// Problem constants
constexpr int kB = 64;     // batch
constexpr int kN = 196;    // tokens in X
constexpr int kC = 512;    // X channels
constexpr int kE = 512;    // embedding dim
constexpr int kH = 1024;   // hidden
constexpr int kV = 10000;  // vocab (= 625*16 exactly)
constexpr int kT = 20;     // steps
constexpr int kG4 = 4 * kH;   // 4096
constexpr int kKA = 1536;     // gates GEMM K (e|h)
constexpr int kLT = 625;      // logit col-tiles of 16

__device__ __forceinline__ float sigmoidf_(float x) { return 1.0f / (1.0f + expf(-x)); }

__device__ __forceinline__ u16 f2bf(float x) {
    unsigned u = __float_as_uint(x);
    u += 0x7FFF + ((u >> 16) & 1);
    return (u16)(u >> 16);
}
__device__ __forceinline__ float bf2f(u16 u) {
    return __uint_as_float((unsigned)u << 16);
}
__device__ __forceinline__ void splitbf(float x, u16& hi, u16& lo) {
    hi = f2bf(x);
    lo = f2bf(x - bf2f(hi));
}

// pack a (logit, col) pair into a monotonic u64 key for atomicMax argmax;
// ties resolve to LOWER index (np.argmax semantics)
__device__ __forceinline__ u64 packMI(float M, int I) {
    unsigned mb = __float_as_uint(M);
    mb = (mb & 0x80000000u) ? ~mb : (mb | 0x80000000u);
    return ((u64)mb << 32) | (u64)(0xFFFFFFFFu - (unsigned)I);
}

// ---------------- setup kernels ----------------

__global__ __launch_bounds__(256) void k_colsum(const float* __restrict__ X,
                                                float* __restrict__ XsP) {
    int gid = blockIdx.x * 256 + threadIdx.x;    // 4*64*512
    int c = gid & 511, b = (gid >> 9) & 63, ch = gid >> 15;
    const float* p = X + (size_t)b * kN * kC + (size_t)(ch * 49) * kC + c;
    float s = 0.f;
    for (int n = 0; n < 49; ++n) s += p[(size_t)n * kC];
    XsP[gid] = s;
}

__global__ __launch_bounds__(256) void k_colred(const float* __restrict__ XsP,
                                                float* __restrict__ XsT) {
    int gid = blockIdx.x * 256 + threadIdx.x;    // 64*512
    int b = gid >> 9, c = gid & 511;
    float s = 0.f;
#pragma unroll
    for (int ch = 0; ch < 4; ++ch) s += XsP[ch * 32768 + b * 512 + c];
    XsT[c * kB + b] = s;
}

// Unified fp32 setup GEMM from XsT (K=512).
__global__ __launch_bounds__(256) void k_setupgemm(const float* __restrict__ XsT,
                                                   const float* __restrict__ W_ih,
                                                   const float* __restrict__ b_ih,
                                                   const float* __restrict__ b_hh,
                                                   const float* __restrict__ Wc0,
                                                   const float* __restrict__ bc0,
                                                   const float* __restrict__ Wh0,
                                                   const float* __restrict__ bh0,
                                                   const float* __restrict__ Wlc,
                                                   const float* __restrict__ blc,
                                                   const float* __restrict__ blh,
                                                   float* __restrict__ gbP,
                                                   float* __restrict__ cBJ,
                                                   u16* __restrict__ hb0Hi,
                                                   u16* __restrict__ hb0Lo,
                                                   float* __restrict__ ctxc) {
    __shared__ float4 wt4[64][8];
    int t = threadIdx.x;
    int b = t & 63, q = t >> 6;
    int tile = blockIdx.x;

    const float* W; const float* bias; float scale; int ldw; int mode; int j;
    if (tile < 128) {
        j = tile * 32; W = W_ih + (size_t)kE * kG4 + j; ldw = kG4;
        bias = nullptr; scale = 1.f; mode = 0;
    } else if (tile < 160) {
        j = (tile - 128) * 32; W = Wc0 + j; ldw = kH;
        bias = bc0 + j; scale = 1.0f / 196.0f; mode = 1;
    } else if (tile < 192) {
        j = (tile - 160) * 32; W = Wh0 + j; ldw = kH;
        bias = bh0 + j; scale = 1.0f / 196.0f; mode = 2;
    } else {
        j = (tile - 192) * 32; W = Wlc + j; ldw = kE;
        bias = blc + j; scale = 1.f; mode = 3;
    }

    int lr = t >> 2, lq2 = (t & 3) * 2;
    float acc[8];
#pragma unroll
    for (int i = 0; i < 8; ++i) acc[i] = 0.f;

    for (int kt = 0; kt < kC; kt += 64) {
        const float* wrow = W + (size_t)(kt + lr) * ldw;
        float4 w0 = *reinterpret_cast<const float4*>(wrow + lq2 * 4);
        float4 w1 = *reinterpret_cast<const float4*>(wrow + lq2 * 4 + 4);
        __syncthreads();
        wt4[lr][lq2] = w0; wt4[lr][lq2 + 1] = w1;
        __syncthreads();
        const float* ap = XsT + (size_t)kt * kB + b;
#pragma unroll 8
        for (int kk = 0; kk < 64; ++kk) {
            float a = ap[kk * 64] * scale;
            float4 u0 = wt4[kk][q * 2];
            float4 u1 = wt4[kk][q * 2 + 1];
            acc[0] += a * u0.x; acc[1] += a * u0.y; acc[2] += a * u0.z; acc[3] += a * u0.w;
            acc[4] += a * u1.x; acc[5] += a * u1.y; acc[6] += a * u1.z; acc[7] += a * u1.w;
        }
    }
#pragma unroll
    for (int cc = 0; cc < 8; ++cc) {
        int col = q * 8 + cc;
        float v = acc[cc];
        if (mode == 0) {
            int jsrc = j + col;
            v += b_ih[jsrc] + b_hh[jsrc];
            int nd = ((jsrc & 1023) << 2) | (jsrc >> 10);
            gbP[(size_t)b * kG4 + nd] = v;
        } else if (mode == 1) {
            v = tanhf(v + bias[col]);
            cBJ[(size_t)b * kH + j + col] = v;
        } else if (mode == 2) {
            v = tanhf(v + bias[col]);
            u16 hi, lo; splitbf(v, hi, lo);
            hb0Hi[(size_t)b * kH + j + col] = hi;
            hb0Lo[(size_t)b * kH + j + col] = lo;
        } else {
            v += bias[col] + blh[j + col];
            ctxc[(size_t)b * kE + j + col] = v;
        }
    }
}

// ---- fused prep kernel: all independent one-time conversions in ONE launch ----
// block ranges: [0,512) Wg-e | [512,1536) Wg-h | [1536,1664) Wlh |
//               [1664,2920) Wout | [2920,7920) emb | [7920,10420) out row0
typedef float LdsT[64][65];

__device__ __forceinline__ void wgconv_body(LdsT& lds, const float* __restrict__ src,
                                            u16* __restrict__ dhi, int k_off, int bid) {
    int t = threadIdx.x;
    int nx = bid & 63, ky = bid >> 6;
    int n0 = nx * 64, k0 = ky * 64;
    int c = t & 63, r0 = t >> 6;
#pragma unroll
    for (int i = 0; i < 16; ++i) {
        int r = r0 + i * 4;
        int nd = n0 + c;
        int nsrc = (nd & 3) * 1024 + (nd >> 2);    // gate-interleave perm
        lds[r][c] = src[(size_t)(k0 + r) * kG4 + nsrc];
    }
    __syncthreads();
    int nl = t >> 2, kq = t & 3;
#pragma unroll
    for (int half = 0; half < 2; ++half) {
        ushort8 vh;
#pragma unroll
        for (int jj = 0; jj < 8; ++jj) vh[jj] = f2bf(lds[kq * 16 + half * 8 + jj][nl]);
        size_t o = (size_t)(n0 + nl) * kKA + k_off + k0 + kq * 16 + half * 8;
        *(ushort8*)(&dhi[o]) = vh;
    }
}

__device__ __forceinline__ void wconvh_body(LdsT& lds, const float* __restrict__ src,
                                            u16* __restrict__ dhi, int ld, int pitch,
                                            int nxTiles, int bid) {
    int t = threadIdx.x;
    int nx = bid % nxTiles, ky = bid / nxTiles;
    int n0 = nx * 64, k0 = ky * 64;
    int c = t & 63, r0 = t >> 6;
#pragma unroll
    for (int i = 0; i < 16; ++i) {
        int r = r0 + i * 4;
        lds[r][c] = src[(size_t)(k0 + r) * ld + n0 + c];
    }
    __syncthreads();
    int nl = t >> 2, kq = t & 3;
#pragma unroll
    for (int half = 0; half < 2; ++half) {
        ushort8 vh;
#pragma unroll
        for (int jj = 0; jj < 8; ++jj) vh[jj] = f2bf(lds[kq * 16 + half * 8 + jj][nl]);
        size_t o = (size_t)(n0 + nl) * pitch + k0 + kq * 16 + half * 8;
        *(ushort8*)(&dhi[o]) = vh;
    }
}

__device__ __forceinline__ void wconv_body(LdsT& lds, const float* __restrict__ src,
                                           u16* __restrict__ dhi, u16* __restrict__ dlo,
                                           int ld, int n_valid, int pitch,
                                           int nxTiles, int bid) {
    int t = threadIdx.x;
    int nx = bid % nxTiles, ky = bid / nxTiles;
    int n0 = nx * 64, k0 = ky * 64;
    int c = t & 63, r0 = t >> 6;
#pragma unroll
    for (int i = 0; i < 16; ++i) {
        int r = r0 + i * 4;
        float v = (n0 + c < n_valid) ? src[(size_t)(k0 + r) * ld + n0 + c] : 0.f;
        lds[r][c] = v;
    }
    __syncthreads();
    int nl = t >> 2, kq = t & 3;
#pragma unroll
    for (int half = 0; half < 2; ++half) {
        ushort8 vh, vl;
#pragma unroll
        for (int jj = 0; jj < 8; ++jj) {
            u16 hi, lo; splitbf(lds[kq * 16 + half * 8 + jj][nl], hi, lo);
            vh[jj] = hi; vl[jj] = lo;
        }
        size_t o = (size_t)(n0 + nl) * pitch + k0 + kq * 16 + half * 8;
        *(ushort8*)(&dhi[o]) = vh;
        *(ushort8*)(&dlo[o]) = vl;
    }
}

__global__ __launch_bounds__(256) void k_prep(const float* __restrict__ W_ih,
                                              const float* __restrict__ W_hh,
                                              const float* __restrict__ Wlh,
                                              const float* __restrict__ Wout,
                                              const float* __restrict__ emb,
                                              u16* __restrict__ WgHi,
                                              u16* __restrict__ WlhHi,
                                              u16* __restrict__ WoHi,
                                              u16* __restrict__ WoLo,
                                              u16* __restrict__ embHi,
                                              u16* __restrict__ embLo,
                                              float* __restrict__ out) {
    __shared__ float lds[64][65];
    int blk = blockIdx.x, t = threadIdx.x;
    if (blk < 512) {
        wgconv_body(lds, W_ih, WgHi, 0, blk);
    } else if (blk < 1536) {
        wgconv_body(lds, W_hh, WgHi, kE, blk - 512);
    } else if (blk < 1664) {
        wconvh_body(lds, Wlh, WlhHi, kE, kH, 8, blk - 1536);
    } else if (blk < 2920) {
        wconv_body(lds, Wout, WoHi, WoLo, kV, kV, kE, 157, blk - 1664);
    } else if (blk < 7920) {
        int gid = (blk - 2920) * 256 + t;    // 1,280,000 quads
        float4 v = *reinterpret_cast<const float4*>(emb + (size_t)gid * 4);
        u16 h0, l0, h1, l1, h2, l2, h3, l3;
        splitbf(v.x, h0, l0); splitbf(v.y, h1, l1);
        splitbf(v.z, h2, l2); splitbf(v.w, h3, l3);
        u64 ph = (u64)h0 | ((u64)h1 << 16) | ((u64)h2 << 32) | ((u64)h3 << 48);
        u64 pl = (u64)l0 | ((u64)l1 << 16) | ((u64)l2 << 32) | ((u64)l3 << 48);
        *reinterpret_cast<u64*>(embHi + (size_t)gid * 4) = ph;
        *reinterpret_cast<u64*>(embLo + (size_t)gid * 4) = pl;
    } else {
        int gid = (blk - 7920) * 256 + t;    // 64*10000
        if (gid < kB * kV) {
            int b = gid / kV, v = gid - b * kV;
            out[(size_t)b * kT * kV + v] = (v == 1) ? 1.0f : 0.0f;
        }
    }
}

// ---------------- per-step kernels (3 per step, kernel-boundary sync) ----------------

struct StepP {
    u16 *hbHi0, *hbLo0, *hbHi1, *hbLo1;   // h activation, double-buffered
    float *cBJ, *gbP, *ctxc;
    u16 *CbHi, *CbLo;
    const u16 *WgHi, *WlhHi, *WoHi, *WoLo, *embHi, *embLo;
    const float *bout;
    float *Ssh;                            // [2][8][64] sum-exp shards
    u64 *Mxsh;                             // [2][8][64] packed (max|~idx) shards
    float *out;
};

// resolve per-batch token of step-1 from Mx shards
__device__ __forceinline__ int resolveTok(const StepP& p, int step, int b) {
    if (step <= 1) return 1;   // START_IDX
    int slot = (step - 1) & 1;
    u64 best = 0;
#pragma unroll
    for (int sh = 0; sh < 8; ++sh) {
        u64 v = p.Mxsh[(slot * 8 + sh) * 64 + b];
        if (v > best) best = v;
    }
    return (int)(0xFFFFFFFFu - (unsigned)(best & 0xFFFFFFFFu));
}

// K1: token resolve + gates GEMM (K=1536, 8-way wave-split-K, W hi-only,
// activations hi+lo -> 2 MFMA) + LSTM. grid 256 x 512 threads.
__global__ __launch_bounds__(512) void k_stepG(StepP p, int step) {
    __shared__ float sred[8][64][17];
    __shared__ int tok[64];
    const int blk = blockIdx.x, t = threadIdx.x;
    const int l = t & 63, w = t >> 6, la = l & 15, lg = l >> 4;
    const int Pb = (step - 1) & 1, Qb = step & 1;

    if (t < 64) tok[t] = resolveTok(p, step, t);
    if (blk < 8 && t < 64) {
        int slot = step & 1;
        p.Ssh[(slot * 8 + blk) * 64 + t] = 0.f;
        p.Mxsh[(slot * 8 + blk) * 64 + t] = 0;
    }
    __syncthreads();

    const u16* hpHi = Pb ? p.hbHi1 : p.hbHi0;
    const u16* hpLo = Pb ? p.hbLo1 : p.hbLo0;
    u16* nHi = Qb ? p.hbHi1 : p.hbHi0;
    u16* nLo = Qb ? p.hbLo1 : p.hbLo0;
    const int n0 = blk * 16;
    const int kb = w * 192 + lg * 8;
    const u16* wh = p.WgHi + (size_t)(n0 + la) * kKA + kb;
    int tk[4];
#pragma unroll
    for (int m = 0; m < 4; ++m) tk[m] = tok[m * 16 + la];

    bf16x8 wreg[6];
#pragma unroll
    for (int ks = 0; ks < 6; ++ks) wreg[ks] = *(const bf16x8*)(wh + ks * 32);

    f32x4 acc[4];
#pragma unroll
    for (int m = 0; m < 4; ++m) acc[m] = (f32x4){0.f, 0.f, 0.f, 0.f};
#pragma unroll
    for (int ks = 0; ks < 6; ++ks) {
        int kc = w * 192 + ks * 32;            // chunk base (wave-uniform)
#pragma unroll
        for (int m = 0; m < 4; ++m) {
            int row = m * 16 + la;
            bf16x8 ahi8, alo8;
            if (kc < kE) {
                size_t o = (size_t)tk[m] * kE + kc + lg * 8;
                ahi8 = *(const bf16x8*)(p.embHi + o);
                alo8 = *(const bf16x8*)(p.embLo + o);
            } else {
                size_t o = (size_t)row * kH + (kc - kE) + lg * 8;
                ahi8 = *(const bf16x8*)(hpHi + o);
                alo8 = *(const bf16x8*)(hpLo + o);
            }
            acc[m] = __builtin_amdgcn_mfma_f32_16x16x32_bf16(ahi8, wreg[ks], acc[m], 0, 0, 0);
            acc[m] = __builtin_amdgcn_mfma_f32_16x16x32_bf16(alo8, wreg[ks], acc[m], 0, 0, 0);
        }
    }
#pragma unroll
    for (int m = 0; m < 4; ++m)
#pragma unroll
        for (int r = 0; r < 4; ++r)
            sred[w][m * 16 + lg * 4 + r][la] = acc[m][r];
    __syncthreads();
    if (t < 256) {
        int b = t & 63, jl = (t >> 6) & 3;
        float g[4];
#pragma unroll
        for (int gi = 0; gi < 4; ++gi) {
            int cc = jl * 4 + gi;
            float s = p.gbP[(size_t)b * kG4 + n0 + cc];
#pragma unroll
            for (int wv = 0; wv < 8; ++wv) s += sred[wv][b][cc];
            g[gi] = s;
        }
        int jp = blk * 4 + jl;
        float cold = p.cBJ[b * kH + jp];
        float c2 = sigmoidf_(g[1]) * cold + sigmoidf_(g[0]) * tanhf(g[2]);
        float h2 = sigmoidf_(g[3]) * tanhf(c2);
        p.cBJ[b * kH + jp] = c2;
        u16 hh, hl; splitbf(h2, hh, hl);
        nHi[(size_t)b * kH + jp] = hh;
        nLo[(size_t)b * kH + jp] = hl;
    }
}

// K2: blocks [0,32): comb GEMM (W hi-only) + e/ctx epilogue;
//     blocks [32,256): in-place log-softmax finalize of out row step-1.
__global__ __launch_bounds__(256) void k_stepC(StepP p, int step) {
    __shared__ float sred[4][64][17];
    __shared__ int tok[64];
    __shared__ float lseArr[64];
    const int blk = blockIdx.x, t = threadIdx.x;
    const int Qb = step & 1;

    if (blk < 32) {
        if (t < 64) tok[t] = resolveTok(p, step, t);
        __syncthreads();
        const u16* hcHi = Qb ? p.hbHi1 : p.hbHi0;
        const u16* hcLo = Qb ? p.hbLo1 : p.hbLo0;
        const int l = t & 63, w = t >> 6, la = l & 15, lg = l >> 4;
        const int n0 = blk * 16;
        const int kb = w * 256 + lg * 8;
        const u16* wh = p.WlhHi + (size_t)(n0 + la) * kH + kb;
        bf16x8 wreg[8];
#pragma unroll
        for (int ks = 0; ks < 8; ++ks) wreg[ks] = *(const bf16x8*)(wh + ks * 32);
        f32x4 acc[4];
#pragma unroll
        for (int m = 0; m < 4; ++m) acc[m] = (f32x4){0.f, 0.f, 0.f, 0.f};
#pragma unroll
        for (int ks = 0; ks < 8; ++ks) {
            int ko = ks * 32;
#pragma unroll
            for (int m = 0; m < 4; ++m) {
                size_t o = (size_t)(m * 16 + la) * kH + kb + ko;
                bf16x8 ahi8 = *(const bf16x8*)(hcHi + o);
                bf16x8 alo8 = *(const bf16x8*)(hcLo + o);
                acc[m] = __builtin_amdgcn_mfma_f32_16x16x32_bf16(ahi8, wreg[ks], acc[m], 0, 0, 0);
                acc[m] = __builtin_amdgcn_mfma_f32_16x16x32_bf16(alo8, wreg[ks], acc[m], 0, 0, 0);
            }
        }
#pragma unroll
        for (int m = 0; m < 4; ++m)
#pragma unroll
            for (int r = 0; r < 4; ++r)
                sred[w][m * 16 + lg * 4 + r][la] = acc[m][r];
        __syncthreads();
        int b = t & 63, cq = t >> 6;
        int tokb = tok[b];
#pragma unroll
        for (int i = 0; i < 4; ++i) {
            int cc = cq * 4 + i;
            int col = (blk * 16) + cc;
            float v = sred[0][b][cc] + sred[1][b][cc] + sred[2][b][cc] + sred[3][b][cc];
            v += bf2f(p.embHi[(size_t)tokb * kE + col]) + bf2f(p.embLo[(size_t)tokb * kE + col]);
            v += p.ctxc[(size_t)b * kE + col];
            u16 hh, hl; splitbf(v, hh, hl);
            p.CbHi[(size_t)b * kE + col] = hh;
            p.CbLo[(size_t)b * kE + col] = hl;
        }
    } else if (step > 1) {
        int slot = (step - 1) & 1;
        if (t < 64) {
            float S = 0.f;
#pragma unroll
            for (int sh = 0; sh < 8; ++sh) S += p.Ssh[(slot * 8 + sh) * 64 + t];
            lseArr[t] = logf(S);
        }
        __syncthreads();
        for (int idx = (blk - 32) * 256 + t; idx < kB * kV; idx += 224 * 256) {
            int b = idx / kV, c = idx - b * kV;
            float* op = &p.out[((size_t)b * kT + (step - 1)) * kV + c];
            float v = __builtin_nontemporal_load(op);
            __builtin_nontemporal_store(v - lseArr[b], op);
        }
    }
}

// K3: logits GEMM, 512 threads, 8-way wave-split-K, full bf16x3, grid 625.
// Writes raw logits DIRECTLY into out row `step` (lse subtracted next step).
__global__ __launch_bounds__(512) void k_stepL(StepP p, int step) {
    __shared__ float sred[8][64][17];
    __shared__ float redM[256], redS[256];
    __shared__ int redI[256];
    const int blk = blockIdx.x, t = threadIdx.x;
    const int l = t & 63, w = t >> 6, la = l & 15, lg = l >> 4;
    int slot = step & 1;
    int shard = blk & 7;
    const int c0 = blk * 16;
    const int kb = w * 64 + lg * 8;
    const u16* wh = p.WoHi + (size_t)(c0 + la) * kE + kb;
    const u16* wl = p.WoLo + (size_t)(c0 + la) * kE + kb;
    const u16* a0h = p.CbHi + (size_t)la * kE + kb;
    const u16* a0l = p.CbLo + (size_t)la * kE + kb;

    bf16x8 wh0 = *(const bf16x8*)(wh);
    bf16x8 wh1 = *(const bf16x8*)(wh + 32);
    bf16x8 wl0 = *(const bf16x8*)(wl);
    bf16x8 wl1 = *(const bf16x8*)(wl + 32);

    f32x4 acc[4];
#pragma unroll
    for (int m = 0; m < 4; ++m) acc[m] = (f32x4){0.f, 0.f, 0.f, 0.f};
#pragma unroll
    for (int m = 0; m < 4; ++m) {
        bf16x8 ah0 = *(const bf16x8*)(a0h + (size_t)m * 16 * kE);
        bf16x8 al0 = *(const bf16x8*)(a0l + (size_t)m * 16 * kE);
        bf16x8 ah1 = *(const bf16x8*)(a0h + (size_t)m * 16 * kE + 32);
        bf16x8 al1 = *(const bf16x8*)(a0l + (size_t)m * 16 * kE + 32);
        acc[m] = __builtin_amdgcn_mfma_f32_16x16x32_bf16(ah0, wh0, acc[m], 0, 0, 0);
        acc[m] = __builtin_amdgcn_mfma_f32_16x16x32_bf16(ah0, wl0, acc[m], 0, 0, 0);
        acc[m] = __builtin_amdgcn_mfma_f32_16x16x32_bf16(al0, wh0, acc[m], 0, 0, 0);
        acc[m] = __builtin_amdgcn_mfma_f32_16x16x32_bf16(ah1, wh1, acc[m], 0, 0, 0);
        acc[m] = __builtin_amdgcn_mfma_f32_16x16x32_bf16(ah1, wl1, acc[m], 0, 0, 0);
        acc[m] = __builtin_amdgcn_mfma_f32_16x16x32_bf16(al1, wh1, acc[m], 0, 0, 0);
    }
#pragma unroll
    for (int m = 0; m < 4; ++m)
#pragma unroll
        for (int r = 0; r < 4; ++r)
            sred[w][m * 16 + lg * 4 + r][la] = acc[m][r];
    __syncthreads();
    if (t < 256) {
        int b = t & 63, cq = (t >> 6) & 3;
        float vals[4];
#pragma unroll
        for (int i = 0; i < 4; ++i) {
            int cc = cq * 4 + i;
            float s = p.bout[c0 + cc];
#pragma unroll
            for (int wv = 0; wv < 8; ++wv) s += sred[wv][b][cc];
            vals[i] = s;
        }
        // raw logits straight into the output row (finalized next step)
        __builtin_nontemporal_store((f32x4){vals[0], vals[1], vals[2], vals[3]},
            (f32x4*)(p.out + ((size_t)b * kT + step) * kV + c0 + cq * 4));
        float m = vals[0]; int mi = 0;
#pragma unroll
        for (int i = 1; i < 4; ++i) if (vals[i] > m) { m = vals[i]; mi = i; }
        float se = 0.f;
#pragma unroll
        for (int i = 0; i < 4; ++i) se += __expf(vals[i] - m);
        redM[t] = m; redS[t] = se; redI[t] = c0 + cq * 4 + mi;
    }
    __syncthreads();
    if (t < 64) {
        float M = redM[t], S = redS[t]; int I = redI[t];
#pragma unroll
        for (int q2 = 1; q2 < 4; ++q2) {
            float m2 = redM[t + q2 * 64], s2 = redS[t + q2 * 64];
            int i2 = redI[t + q2 * 64];
            float Mn = fmaxf(M, m2);
            S = S * __expf(M - Mn) + s2 * __expf(m2 - Mn);
            if (m2 > M || (m2 == M && i2 < I)) I = i2;
            M = Mn;
        }
        float S0 = S * __expf(M);   // fold to absolute scale (M=0 reference)
        atomicAdd(&p.Ssh[(slot * 8 + shard) * 64 + t], S0);
        atomicMax(&p.Mxsh[(slot * 8 + shard) * 64 + t], packMI(M, I));
    }
}

// final in-place log-softmax for row kT-1. grid 256.
__global__ __launch_bounds__(256) void k_stepO(StepP p) {
    __shared__ float lseArr[64];
    const int blk = blockIdx.x, t = threadIdx.x;
    int slot = (kT - 1) & 1;
    if (t < 64) {
        float S = 0.f;
#pragma unroll
        for (int sh = 0; sh < 8; ++sh) S += p.Ssh[(slot * 8 + sh) * 64 + t];
        lseArr[t] = logf(S);
    }
    __syncthreads();
    for (int idx = blk * 256 + t; idx < kB * kV; idx += 256 * 256) {
        int b = idx / kV, c = idx - b * kV;
        float* op = &p.out[((size_t)b * kT + (kT - 1)) * kV + c];
        float v = __builtin_nontemporal_load(op);
        __builtin_nontemporal_store(v - lseArr[b], op);
    }
}

// ---------------- launcher ----------------

extern "C" void kernel_launch(void* const* d_in, const int* in_sizes, int n_in,
                              void* d_out, int out_size, void* d_ws, size_t ws_size,
                              hipStream_t stream) {
    const float* X    = (const float*)d_in[0];
    const float* emb  = (const float*)d_in[1];
    const float* W_ih = (const float*)d_in[2];
    const float* b_ih = (const float*)d_in[3];
    const float* W_hh = (const float*)d_in[4];
    const float* b_hh = (const float*)d_in[5];
    // d_in[6..11]: Wa, ba, Wh, bh, Wo, bo — dead (softmax over size-1 axis => weights==1)
    const float* Wlh  = (const float*)d_in[12];
    const float* blh  = (const float*)d_in[13];
    const float* Wlc  = (const float*)d_in[14];
    const float* blc  = (const float*)d_in[15];
    const float* Wout = (const float*)d_in[16];
    const float* bout = (const float*)d_in[17];
    const float* Wc0  = (const float*)d_in[18];
    const float* bc0  = (const float*)d_in[19];
    const float* Wh0  = (const float*)d_in[20];
    const float* bh0  = (const float*)d_in[21];
    float* out = (float*)d_out;

    char* cur = (char*)d_ws;
    auto carve = [&](size_t bytes) { char* p = cur; cur += (bytes + 255) & ~(size_t)255; return p; };

    u16* hbHi0 = (u16*)carve((size_t)kB * kH * 2);
    u16* hbLo0 = (u16*)carve((size_t)kB * kH * 2);
    u16* hbHi1 = (u16*)carve((size_t)kB * kH * 2);
    u16* hbLo1 = (u16*)carve((size_t)kB * kH * 2);
    float* cBJ  = (float*)carve((size_t)kB * kH * 4);
    float* gbP  = (float*)carve((size_t)kB * kG4 * 4);
    float* ctxc = (float*)carve((size_t)kB * kE * 4);
    u16* CbHi   = (u16*)carve((size_t)kB * kE * 2);
    u16* CbLo   = (u16*)carve((size_t)kB * kE * 2);
    float* XsT  = (float*)carve((size_t)kC * kB * 4);
    float* XsP  = (float*)carve((size_t)4 * kB * kC * 4);
    u16* WgHi   = (u16*)carve((size_t)kG4 * kKA * 2);
    u16* WlhHi  = (u16*)carve((size_t)kE * kH * 2);
    u16* WoHi   = (u16*)carve((size_t)10048 * kE * 2);
    u16* WoLo   = (u16*)carve((size_t)10048 * kE * 2);
    u16* embHi  = (u16*)carve((size_t)10000 * kE * 2);
    u16* embLo  = (u16*)carve((size_t)10000 * kE * 2);
    float* Ssh   = (float*)carve((size_t)2 * 8 * 64 * 4);
    u64*   Mxsh  = (u64*)carve((size_t)2 * 8 * 64 * 8);

    // one-time setup: dependent chain (3 launches) + fused independent prep (1 launch)
    k_colsum<<<512, 256, 0, stream>>>(X, XsP);
    k_colred<<<128, 256, 0, stream>>>(XsP, XsT);
    k_setupgemm<<<208, 256, 0, stream>>>(XsT, W_ih, b_ih, b_hh, Wc0, bc0,
                                         Wh0, bh0, Wlc, blc, blh,
                                         gbP, cBJ, hbHi0, hbLo0, ctxc);
    k_prep<<<10420, 256, 0, stream>>>(W_ih, W_hh, Wlh, Wout, emb,
                                      WgHi, WlhHi, WoHi, WoLo, embHi, embLo, out);

    StepP sp;
    sp.hbHi0 = hbHi0; sp.hbLo0 = hbLo0; sp.hbHi1 = hbHi1; sp.hbLo1 = hbLo1;
    sp.cBJ = cBJ; sp.gbP = gbP; sp.ctxc = ctxc;
    sp.CbHi = CbHi; sp.CbLo = CbLo;
    sp.WgHi = WgHi; sp.WlhHi = WlhHi;
    sp.WoHi = WoHi; sp.WoLo = WoLo; sp.embHi = embHi; sp.embLo = embLo;
    sp.bout = bout;
    sp.Ssh = Ssh; sp.Mxsh = Mxsh;
    sp.out = out;

    for (int s = 1; s < kT; ++s) {
        k_stepG<<<256, 512, 0, stream>>>(sp, s);
        k_stepC<<<256, 256, 0, stream>>>(sp, s);
        k_stepL<<<kLT, 512, 0, stream>>>(sp, s);
    }
    k_stepO<<<256, 256, 0, stream>>>(sp);
}